// Round 5
// baseline (7630.049 us; speedup 1.0000x reference)
//
#include <hip/hip_runtime.h>
#include <hip/hip_bf16.h>

typedef short short8 __attribute__((ext_vector_type(8)));
typedef float f32x4 __attribute__((ext_vector_type(4)));

#define BROWS 64
#define NTHR  512
#define XK    96
#define XSTR  104
#define HSTR  264
#define HIDSTR 129
#define NKT0  11
#define NKT1  16
#define NKTO  8
#define PK0_ELEMS (64*NKT0*512)
#define PK1_ELEMS (64*NKT1*512)
#define PKO_ELEMS (8*NKTO*512)

// LDS layout (bytes)
#define L_X    0
#define L_H0   13312
#define L_H1   80896
#define L_HID  114688
#define L_OW2  147712
#define L_OB2  149248
#define LDS_TOTAL 149264
#define H0BUF  (BROWS*HSTR)   // ushort elems per H0 buffer

__device__ inline unsigned short f2bf(float x){
  unsigned u = __float_as_uint(x);
  u += 0x7FFFu + ((u >> 16) & 1u);
  return (unsigned short)(u >> 16);
}
__device__ inline float bf2f(unsigned short s){ return __uint_as_float(((unsigned)s) << 16); }
__device__ inline float sigm(float x){ return 1.f / (1.f + __expf(-x)); }
__device__ inline float ftanh(float x){ float e = __expf(2.f*x); return 1.f - 2.f/(e + 1.f); }

// ---------------- weight pre-pack: fp32 -> single bf16, MFMA B-fragment lane order ----
// layout (ushort): region base + ((ntG*NKT + kt)*64 + lane)*8 + j
// B-frag (16x16x32): lane l holds B[k=(l>>4)*8+j][n=l&15], j=0..7
__global__ void pack_weights(const float* __restrict__ wih0, const float* __restrict__ whh0,
                             const float* __restrict__ wih1, const float* __restrict__ whh1,
                             const float* __restrict__ ow1,
                             unsigned short* __restrict__ wsb){
  int idx = blockIdx.x * blockDim.x + threadIdx.x;
  int total = PK0_ELEMS + PK1_ELEMS + PKO_ELEMS;
  if (idx >= total) return;
  float w;
  size_t off;
  if (idx < PK0_ELEMS) {
    int nt = idx / (NKT0*512), rem = idx % (NKT0*512), kt = rem / 512, li = rem % 512;
    int lane = li >> 3, j = li & 7;
    int n = lane & 15, k = ((lane >> 4) << 3) + j;
    int Kg = kt*32 + k, g = nt*16 + n;
    // K-space: [0..2]=cur, [3..66]=z, [67..72]=cond (w_ih0 cols 0..72), [73..95]=pad0, [96..351]=w_hh0
    if (Kg < 73)       w = wih0[g*73 + Kg];
    else if (Kg < XK)  w = 0.f;
    else               w = whh0[g*256 + (Kg - XK)];
    off = ((size_t)(nt*NKT0 + kt)*64 + lane)*8 + j;
  } else if (idx < PK0_ELEMS + PK1_ELEMS) {
    int i2 = idx - PK0_ELEMS;
    int nt = i2 / (NKT1*512), rem = i2 % (NKT1*512), kt = rem / 512, li = rem % 512;
    int lane = li >> 3, j = li & 7;
    int n = lane & 15, k = ((lane >> 4) << 3) + j;
    int Kg = kt*32 + k, g = nt*16 + n;
    w = (Kg < 256) ? wih1[g*256 + Kg] : whh1[g*256 + (Kg - 256)];
    off = (size_t)PK0_ELEMS + ((size_t)(nt*NKT1 + kt)*64 + lane)*8 + j;
  } else {
    int i2 = idx - PK0_ELEMS - PK1_ELEMS;
    int nt = i2 / (NKTO*512), rem = i2 % (NKTO*512), kt = rem / 512, li = rem % 512;
    int lane = li >> 3, j = li & 7;
    int n = lane & 15, k = ((lane >> 4) << 3) + j;
    int Kg = kt*32 + k, uh = nt*16 + n;
    w = ow1[uh*256 + Kg];
    off = (size_t)PK0_ELEMS + (size_t)PK1_ELEMS + ((size_t)(nt*NKTO + kt)*64 + lane)*8 + j;
  }
  wsb[off] = f2bf(w);
}

// ---------------- persistent rollout kernel ----------------
// __launch_bounds__(512, 2): 2nd arg = MIN WAVES PER EU (SIMD) on AMD HIP.
// LDS (149KB) caps us at 1 block/CU = 2 waves/SIMD anyway; declaring it raises the
// per-wave VGPR cap to 256 so the ~200-reg live set (acc 64 + c-state 64 + ring 32
// + frags) fits WITHOUT scratch spills. R4 evidence: at cap 128, spills wrote
// 1.6GB/dispatch to scratch, polluting L2 and forcing 13GB of HBM weight re-fetch.
__global__ void __launch_bounds__(NTHR, 2)
traj_main(const float* __restrict__ z, const float* __restrict__ cond,
          const float* __restrict__ fiw, const float* __restrict__ fib,
          const float* __restrict__ bih0, const float* __restrict__ bhh0,
          const float* __restrict__ bih1, const float* __restrict__ bhh1,
          const float* __restrict__ ob1,  const float* __restrict__ ow2,
          const float* __restrict__ ob2,
          const unsigned short* __restrict__ wsb, const int* __restrict__ seqp,
          float* __restrict__ out){
  extern __shared__ char smem[];
  unsigned short* Xl  = (unsigned short*)(smem + L_X);    // [64][104] bf16: cur|z|cond|pad
  unsigned short* H0l = (unsigned short*)(smem + L_H0);   // [2][64][264] bf16
  unsigned short* H1l = (unsigned short*)(smem + L_H1);   // [64][264] bf16
  float*          HIDl= (float*)(smem + L_HID);           // [64][129] f32
  float*          OW2l= (float*)(smem + L_OW2);           // [3][128]
  float*          OB2l= (float*)(smem + L_OB2);           // [3]

  const int tid = threadIdx.x, wv = tid >> 6, lane = tid & 63;
  const int bid = blockIdx.x;
  const int row0 = bid * BROWS;
  const int T = *seqp;

  const unsigned short* pk0i = wsb;
  const unsigned short* pk1i = wsb + (size_t)PK0_ELEMS;
  const unsigned short* pkoi = wsb + (size_t)PK0_ELEMS + (size_t)PK1_ELEMS;

  // ---- init: fill X (cur0 = cond[:3], z, cond), copy ow2/ob2 to LDS
  {
    int r = tid >> 3, seg = tid & 7;
    int gr = row0 + r;
    for (int c = seg*13; c < seg*13 + 13; ++c) {
      float v;
      if (c < 3)       v = cond[gr*6 + c];
      else if (c < 67) v = z[gr*64 + (c - 3)];
      else if (c < 73) v = cond[gr*6 + (c - 67)];
      else             v = 0.f;
      Xl[r*XSTR + c] = f2bf(v);
    }
  }
  if (tid < 384) OW2l[tid] = ow2[tid];
  if (tid < 3)   OB2l[tid] = ob2[tid];

  // ---- init h0, h1 = zc @ fc_init_w.T + fc_init_b  (fp32 VALU, one-time)
  {
    int r = tid >> 3, ub = (tid & 7) * 32;
    int gr = row0 + r;
    #pragma unroll 1
    for (int u = ub; u < ub + 32; ++u) {
      float s0 = fib[u], s1 = fib[256 + u];
      const float* w0r = fiw + (size_t)u * 70;
      const float* w1r = fiw + (size_t)(256 + u) * 70;
      for (int jj = 0; jj < 64; ++jj) { float xv = z[gr*64 + jj]; s0 += xv * w0r[jj]; s1 += xv * w1r[jj]; }
      for (int jj = 0; jj < 6;  ++jj) { float xv = cond[gr*6 + jj]; s0 += xv * w0r[64 + jj]; s1 += xv * w1r[64 + jj]; }
      H0l[r*HSTR + u] = f2bf(s0);
      H1l[r*HSTR + u] = f2bf(s1);
    }
  }

  // ---- per-lane bias preload (unit u depends on pass p)
  float bias0r[8], bias1r[8];
  #pragma unroll
  for (int p = 0; p < 2; ++p) {
    int u = wv*32 + p*16 + (lane & 15);
    #pragma unroll
    for (int g = 0; g < 4; ++g) {
      bias0r[p*4 + g] = bih0[g*256 + u] + bhh0[g*256 + u];
      bias1r[p*4 + g] = bih1[g*256 + u] + bhh1[g*256 + u];
    }
  }
  float ob1r = ob1[wv*16 + (lane & 15)];

  // ---- c-state in registers (fixed (row,unit)->lane mapping from MFMA C layout)
  float c0s[32], c1s[32];
  #pragma unroll
  for (int i = 0; i < 32; ++i) { c0s[i] = 0.f; c1s[i] = 0.f; }

  float h1n_s[32];

  __syncthreads();

  const int arow = lane & 15, koff = (lane >> 4) * 8;

  int pb = 0;
  for (int t = 0; t < T; ++t) {
    // ===== M1: gates0 = [x|h0] @ W0^T (+b), LSTM cell 0; h0n -> H0[pb^1] =====
    #pragma unroll
    for (int p = 0; p < 2; ++p) {
      // weight base for this pass; g-stride = 16 ntG * NKT0 * 512 ushorts
      const unsigned short* wb = pk0i + ((size_t)((wv*2 + p)*NKT0)*64 + lane)*8;

      // depth-2 prefetch ring
      short8 wh[3][4];
      #pragma unroll
      for (int g = 0; g < 4; ++g) {
        const unsigned short* q0 = wb + (size_t)g*(16*NKT0*512);
        wh[0][g] = *(const short8*)(q0);
        wh[1][g] = *(const short8*)(q0 + 512);
      }

      f32x4 acc[4][4];
      #pragma unroll
      for (int mt = 0; mt < 4; ++mt)
        #pragma unroll
        for (int g = 0; g < 4; ++g) {
          float b = bias0r[p*4 + g];
          acc[mt][g] = (f32x4){b, b, b, b};
        }

      #pragma unroll
      for (int kt = 0; kt < NKT0; ++kt) {
        const int cb = kt % 3, nb2 = (kt + 2) % 3;
        if (kt + 2 < NKT0) {
          #pragma unroll
          for (int g = 0; g < 4; ++g)
            wh[nb2][g] = *(const short8*)(wb + (size_t)g*(16*NKT0*512) + (size_t)(kt+2)*512);
        }
        short8 a[4];
        if (kt < 3) {
          #pragma unroll
          for (int mt = 0; mt < 4; ++mt)
            a[mt] = *(const short8*)(Xl + (mt*16 + arow)*XSTR + kt*32 + koff);
        } else {
          const unsigned short* hb = H0l + pb*H0BUF;
          #pragma unroll
          for (int mt = 0; mt < 4; ++mt)
            a[mt] = *(const short8*)(hb + (mt*16 + arow)*HSTR + (kt - 3)*32 + koff);
        }
        #pragma unroll
        for (int g = 0; g < 4; ++g)
          #pragma unroll
          for (int mt = 0; mt < 4; ++mt)
            acc[mt][g] = __builtin_amdgcn_mfma_f32_16x16x32_bf16(a[mt], wh[cb][g], acc[mt][g], 0, 0, 0);
      }

      const int u = wv*32 + p*16 + (lane & 15);
      #pragma unroll
      for (int mt = 0; mt < 4; ++mt) {
        #pragma unroll
        for (int q = 0; q < 4; ++q) {
          float iv = sigm(acc[mt][0][q]);
          float fv = sigm(acc[mt][1][q]);
          float gv = ftanh(acc[mt][2][q]);
          float ov = sigm(acc[mt][3][q]);
          float cn = fv * c0s[(p*4 + mt)*4 + q] + iv * gv;
          c0s[(p*4 + mt)*4 + q] = cn;
          float hn = ov * ftanh(cn);
          int r = mt*16 + ((lane >> 4) << 2) + q;
          H0l[(pb ^ 1)*H0BUF + r*HSTR + u] = f2bf(hn);
        }
      }
    }
    __syncthreads();  // B1: h0n complete

    // ===== M2: gates1 = [h0n|h1] @ W1^T (+b), LSTM cell 1; h1n stashed in regs =====
    #pragma unroll
    for (int p = 0; p < 2; ++p) {
      const unsigned short* wb = pk1i + ((size_t)((wv*2 + p)*NKT1)*64 + lane)*8;

      short8 wh[3][4];
      #pragma unroll
      for (int g = 0; g < 4; ++g) {
        const unsigned short* q0 = wb + (size_t)g*(16*NKT1*512);
        wh[0][g] = *(const short8*)(q0);
        wh[1][g] = *(const short8*)(q0 + 512);
      }

      f32x4 acc[4][4];
      #pragma unroll
      for (int mt = 0; mt < 4; ++mt)
        #pragma unroll
        for (int g = 0; g < 4; ++g) {
          float b = bias1r[p*4 + g];
          acc[mt][g] = (f32x4){b, b, b, b};
        }

      #pragma unroll
      for (int kt = 0; kt < NKT1; ++kt) {
        const int cb = kt % 3, nb2 = (kt + 2) % 3;
        if (kt + 2 < NKT1) {
          #pragma unroll
          for (int g = 0; g < 4; ++g)
            wh[nb2][g] = *(const short8*)(wb + (size_t)g*(16*NKT1*512) + (size_t)(kt+2)*512);
        }
        short8 a[4];
        if (kt < 8) {
          const unsigned short* hb = H0l + (pb ^ 1)*H0BUF;
          #pragma unroll
          for (int mt = 0; mt < 4; ++mt)
            a[mt] = *(const short8*)(hb + (mt*16 + arow)*HSTR + kt*32 + koff);
        } else {
          #pragma unroll
          for (int mt = 0; mt < 4; ++mt)
            a[mt] = *(const short8*)(H1l + (mt*16 + arow)*HSTR + (kt - 8)*32 + koff);
        }
        #pragma unroll
        for (int g = 0; g < 4; ++g)
          #pragma unroll
          for (int mt = 0; mt < 4; ++mt)
            acc[mt][g] = __builtin_amdgcn_mfma_f32_16x16x32_bf16(a[mt], wh[cb][g], acc[mt][g], 0, 0, 0);
      }

      #pragma unroll
      for (int mt = 0; mt < 4; ++mt) {
        #pragma unroll
        for (int q = 0; q < 4; ++q) {
          float iv = sigm(acc[mt][0][q]);
          float fv = sigm(acc[mt][1][q]);
          float gv = ftanh(acc[mt][2][q]);
          float ov = sigm(acc[mt][3][q]);
          float cn = fv * c1s[(p*4 + mt)*4 + q] + iv * gv;
          c1s[(p*4 + mt)*4 + q] = cn;
          h1n_s[(p*4 + mt)*4 + q] = ov * ftanh(cn);
        }
      }
    }
    __syncthreads();  // B2: all H1 reads done

    #pragma unroll
    for (int p = 0; p < 2; ++p) {
      const int u = wv*32 + p*16 + (lane & 15);
      #pragma unroll
      for (int mt = 0; mt < 4; ++mt)
        #pragma unroll
        for (int q = 0; q < 4; ++q) {
          int r = mt*16 + ((lane >> 4) << 2) + q;
          H1l[r*HSTR + u] = f2bf(h1n_s[(p*4 + mt)*4 + q]);
        }
    }
    __syncthreads();  // B3: h1n visible

    // ===== M3: hid = relu(h1n @ out_w1^T + out_b1) -> LDS fp32 =====
    {
      const unsigned short* wb = pkoi + ((size_t)(wv*NKTO)*64 + lane)*8;
      short8 wh[3];
      wh[0] = *(const short8*)(wb);
      wh[1] = *(const short8*)(wb + 512);

      f32x4 acc3[4];
      #pragma unroll
      for (int mt = 0; mt < 4; ++mt) acc3[mt] = (f32x4){ob1r, ob1r, ob1r, ob1r};

      #pragma unroll
      for (int kt = 0; kt < NKTO; ++kt) {
        const int cb = kt % 3, nb2 = (kt + 2) % 3;
        if (kt + 2 < NKTO)
          wh[nb2] = *(const short8*)(wb + (size_t)(kt+2)*512);
        short8 a[4];
        #pragma unroll
        for (int mt = 0; mt < 4; ++mt)
          a[mt] = *(const short8*)(H1l + (mt*16 + arow)*HSTR + kt*32 + koff);
        #pragma unroll
        for (int mt = 0; mt < 4; ++mt)
          acc3[mt] = __builtin_amdgcn_mfma_f32_16x16x32_bf16(a[mt], wh[cb], acc3[mt], 0, 0, 0);
      }
      const int uh = wv*16 + (lane & 15);
      #pragma unroll
      for (int mt = 0; mt < 4; ++mt)
        #pragma unroll
        for (int q = 0; q < 4; ++q) {
          float hv = fmaxf(acc3[mt][q], 0.f);
          int r = mt*16 + ((lane >> 4) << 2) + q;
          HIDl[r*HIDSTR + uh] = hv;
        }
    }
    __syncthreads();  // B4: hid visible

    // ===== M4: out = hid @ out_w2^T + out_b2, all 512 threads:
    // 8 threads per row, 16-wide k-partials, shfl-reduce width 8 =====
    {
      int r = tid >> 3, e = tid & 7;
      const float* hrow = HIDl + r*HIDSTR + e*16;
      float s0 = 0.f, s1 = 0.f, s2 = 0.f;
      #pragma unroll
      for (int k = 0; k < 16; ++k) {
        float hv = hrow[k];
        int kk = e*16 + k;
        s0 += hv * OW2l[kk];
        s1 += hv * OW2l[128 + kk];
        s2 += hv * OW2l[256 + kk];
      }
      #pragma unroll
      for (int d = 4; d; d >>= 1) {
        s0 += __shfl_down(s0, d, 8);
        s1 += __shfl_down(s1, d, 8);
        s2 += __shfl_down(s2, d, 8);
      }
      if (e == 0) {
        s0 += OB2l[0]; s1 += OB2l[1]; s2 += OB2l[2];
        int gr = row0 + r;
        float* orow = out + (size_t)gr * (T*3) + t*3;
        orow[0] = s0; orow[1] = s1; orow[2] = s2;
        Xl[r*XSTR + 0] = f2bf(s0);
        Xl[r*XSTR + 1] = f2bf(s1);
        Xl[r*XSTR + 2] = f2bf(s2);
      }
    }
    __syncthreads();  // B5: cur visible, hid reads done

    pb ^= 1;
  }
}

extern "C" void kernel_launch(void* const* d_in, const int* in_sizes, int n_in,
                              void* d_out, int out_size, void* d_ws, size_t ws_size,
                              hipStream_t stream){
  const float* z    = (const float*)d_in[0];
  const float* cond = (const float*)d_in[1];
  const float* fiw  = (const float*)d_in[2];
  const float* fib  = (const float*)d_in[3];
  const float* wih0 = (const float*)d_in[4];
  const float* whh0 = (const float*)d_in[5];
  const float* bih0 = (const float*)d_in[6];
  const float* bhh0 = (const float*)d_in[7];
  const float* wih1 = (const float*)d_in[8];
  const float* whh1 = (const float*)d_in[9];
  const float* bih1 = (const float*)d_in[10];
  const float* bhh1 = (const float*)d_in[11];
  const float* ow1  = (const float*)d_in[12];
  const float* ob1  = (const float*)d_in[13];
  const float* ow2  = (const float*)d_in[14];
  const float* ob2  = (const float*)d_in[15];
  const int*   seqp = (const int*)d_in[16];
  unsigned short* wsb = (unsigned short*)d_ws;
  float* outp = (float*)d_out;

  hipFuncSetAttribute((const void*)traj_main,
                      hipFuncAttributeMaxDynamicSharedMemorySize, LDS_TOTAL);

  int packtot = PK0_ELEMS + PK1_ELEMS + PKO_ELEMS;
  pack_weights<<<(packtot + 255)/256, 256, 0, stream>>>(wih0, whh0, wih1, whh1, ow1, wsb);
  traj_main<<<16384/BROWS, NTHR, LDS_TOTAL, stream>>>(z, cond, fiw, fib,
                                                      bih0, bhh0, bih1, bhh1,
                                                      ob1, ow2, ob2, wsb, seqp, outp);
}

// Round 6
// 5731.866 us; speedup vs baseline: 1.3312x; 1.3312x over previous
//
#include <hip/hip_runtime.h>
#include <hip/hip_bf16.h>

typedef short short8 __attribute__((ext_vector_type(8)));
typedef float f32x4 __attribute__((ext_vector_type(4)));

#define BROWS 64
#define NTHR  512
#define XK    96
#define XSTR  104
#define HSTR  264
#define HIDSTR 129
#define NKT0  11
#define NKT1  16
#define NKTO  8
#define PK0_ELEMS (64*NKT0*512)
#define PK1_ELEMS (64*NKT1*512)
#define PKO_ELEMS (8*NKTO*512)

// LDS layout (bytes)
#define L_X    0
#define L_H    13312
#define HBUF   (BROWS*HSTR)          // ushort elems per H buffer (3 rotating buffers)
#define HBUF_B (HBUF*2)              // bytes
#define L_HID  (L_H + 3*HBUF_B)      // 114688
#define L_OW2  (L_HID + 33024)       // 147712
#define L_OB2  (L_OW2 + 1536)        // 149248
#define LDS_TOTAL 149264

__device__ inline unsigned short f2bf(float x){
  unsigned u = __float_as_uint(x);
  u += 0x7FFFu + ((u >> 16) & 1u);
  return (unsigned short)(u >> 16);
}
__device__ inline float bf2f(unsigned short s){ return __uint_as_float(((unsigned)s) << 16); }
__device__ inline float sigm(float x){ return 1.f / (1.f + __expf(-x)); }
__device__ inline float ftanh(float x){ float e = __expf(2.f*x); return 1.f - 2.f/(e + 1.f); }

// ---------------- weight pre-pack: fp32 -> single bf16, MFMA B-fragment lane order ----
// layout (ushort): region base + ((ntG*NKT + kt)*64 + lane)*8 + j
// B-frag (16x16x32): lane l holds B[k=(l>>4)*8+j][n=l&15], j=0..7
// Layer-0 K-space: [0..2]=cur, [3..66]=z, [67..72]=cond, [73]=BIAS (X col 73 == 1.0),
//                  [74..95]=pad0, [96..351]=w_hh0
__global__ void pack_weights(const float* __restrict__ wih0, const float* __restrict__ whh0,
                             const float* __restrict__ bih0, const float* __restrict__ bhh0,
                             const float* __restrict__ wih1, const float* __restrict__ whh1,
                             const float* __restrict__ ow1,
                             unsigned short* __restrict__ wsb){
  int idx = blockIdx.x * blockDim.x + threadIdx.x;
  int total = PK0_ELEMS + PK1_ELEMS + PKO_ELEMS;
  if (idx >= total) return;
  float w;
  size_t off;
  if (idx < PK0_ELEMS) {
    int nt = idx / (NKT0*512), rem = idx % (NKT0*512), kt = rem / 512, li = rem % 512;
    int lane = li >> 3, j = li & 7;
    int n = lane & 15, k = ((lane >> 4) << 3) + j;
    int Kg = kt*32 + k, g = nt*16 + n;          // g = global gate-unit index [0,1024)
    if (Kg < 73)        w = wih0[g*73 + Kg];
    else if (Kg == 73)  w = bih0[g] + bhh0[g];  // bias via constant-1 input column
    else if (Kg < XK)   w = 0.f;
    else                w = whh0[g*256 + (Kg - XK)];
    off = ((size_t)(nt*NKT0 + kt)*64 + lane)*8 + j;
  } else if (idx < PK0_ELEMS + PK1_ELEMS) {
    int i2 = idx - PK0_ELEMS;
    int nt = i2 / (NKT1*512), rem = i2 % (NKT1*512), kt = rem / 512, li = rem % 512;
    int lane = li >> 3, j = li & 7;
    int n = lane & 15, k = ((lane >> 4) << 3) + j;
    int Kg = kt*32 + k, g = nt*16 + n;
    w = (Kg < 256) ? wih1[g*256 + Kg] : whh1[g*256 + (Kg - 256)];
    off = (size_t)PK0_ELEMS + ((size_t)(nt*NKT1 + kt)*64 + lane)*8 + j;
  } else {
    int i2 = idx - PK0_ELEMS - PK1_ELEMS;
    int nt = i2 / (NKTO*512), rem = i2 % (NKTO*512), kt = rem / 512, li = rem % 512;
    int lane = li >> 3, j = li & 7;
    int n = lane & 15, k = ((lane >> 4) << 3) + j;
    int Kg = kt*32 + k, uh = nt*16 + n;
    w = ow1[uh*256 + Kg];
    off = (size_t)PK0_ELEMS + (size_t)PK1_ELEMS + ((size_t)(nt*NKTO + kt)*64 + lane)*8 + j;
  }
  wsb[off] = f2bf(w);
}

// ---------------- persistent rollout kernel ----------------
// __launch_bounds__(512, 1): R1-R5 evidence shows arg2=2 produced a 128-VGPR cap
// (4 waves/SIMD budget) -> 229 B/thread/step of c-state spills (WRITE_SIZE 1.5GB)
// thrashing L2. With arg2=1, under EITHER documented interpretation the cap is 256:
// flat workgroup 512 = 8 waves needs >=2 waves/SIMD, so the allocator cannot
// exceed 256/wave anyway. Live set ~220 regs fits in 256.
__global__ void __launch_bounds__(NTHR, 1)
traj_main(const float* __restrict__ z, const float* __restrict__ cond,
          const float* __restrict__ fiw, const float* __restrict__ fib,
          const float* __restrict__ bih1, const float* __restrict__ bhh1,
          const float* __restrict__ ob1,  const float* __restrict__ ow2,
          const float* __restrict__ ob2,
          const unsigned short* __restrict__ wsb, const int* __restrict__ seqp,
          float* __restrict__ out){
  extern __shared__ char smem[];
  unsigned short* Xl  = (unsigned short*)(smem + L_X);    // [64][104] bf16: cur|z|cond|1|pad
  unsigned short* Hl  = (unsigned short*)(smem + L_H);    // 3 x [64][264] bf16 rotating
  float*          HIDl= (float*)(smem + L_HID);           // [64][129] f32
  float*          OW2l= (float*)(smem + L_OW2);           // [3][128]
  float*          OB2l= (float*)(smem + L_OB2);           // [3]

  const int tid = threadIdx.x, wv = tid >> 6, lane = tid & 63;
  const int bid = blockIdx.x;
  const int row0 = bid * BROWS;
  const int T = *seqp;

  const unsigned short* pk0i = wsb;
  const unsigned short* pk1i = wsb + (size_t)PK0_ELEMS;
  const unsigned short* pkoi = wsb + (size_t)PK0_ELEMS + (size_t)PK1_ELEMS;

  // ---- init: fill X (cur0 = cond[:3], z, cond, 1.0 bias col), copy ow2/ob2 to LDS
  {
    int r = tid >> 3, seg = tid & 7;
    int gr = row0 + r;
    for (int c = seg*13; c < seg*13 + 13; ++c) {
      float v;
      if (c < 3)        v = cond[gr*6 + c];
      else if (c < 67)  v = z[gr*64 + (c - 3)];
      else if (c < 73)  v = cond[gr*6 + (c - 67)];
      else if (c == 73) v = 1.0f;               // bias multiplier column
      else              v = 0.f;
      Xl[r*XSTR + c] = f2bf(v);
    }
  }
  if (tid < 384) OW2l[tid] = ow2[tid];
  if (tid < 3)   OB2l[tid] = ob2[tid];

  // ---- init h0 -> H[0], h1 -> H[1]  (fp32 VALU, one-time)
  {
    int r = tid >> 3, ub = (tid & 7) * 32;
    int gr = row0 + r;
    #pragma unroll 1
    for (int u = ub; u < ub + 32; ++u) {
      float s0 = fib[u], s1 = fib[256 + u];
      const float* w0r = fiw + (size_t)u * 70;
      const float* w1r = fiw + (size_t)(256 + u) * 70;
      for (int jj = 0; jj < 64; ++jj) { float xv = z[gr*64 + jj]; s0 += xv * w0r[jj]; s1 += xv * w1r[jj]; }
      for (int jj = 0; jj < 6;  ++jj) { float xv = cond[gr*6 + jj]; s0 += xv * w0r[64 + jj]; s1 += xv * w1r[64 + jj]; }
      Hl[0*HBUF + r*HSTR + u] = f2bf(s0);
      Hl[1*HBUF + r*HSTR + u] = f2bf(s1);
    }
  }

  // ---- per-lane layer-1 bias preload (layer-0 bias folded into weights)
  float bias1r[8];
  #pragma unroll
  for (int p = 0; p < 2; ++p) {
    int u = wv*32 + p*16 + (lane & 15);
    #pragma unroll
    for (int g = 0; g < 4; ++g)
      bias1r[p*4 + g] = bih1[g*256 + u] + bhh1[g*256 + u];
  }
  float ob1r = ob1[wv*16 + (lane & 15)];

  // ---- c-state in registers (fixed (row,unit)->lane mapping from MFMA C layout)
  float c0s[32], c1s[32];
  #pragma unroll
  for (int i = 0; i < 32; ++i) { c0s[i] = 0.f; c1s[i] = 0.f; }

  __syncthreads();

  const int arow = lane & 15, koff = (lane >> 4) * 8;

  // rotating buffer roles: ia = h0(t), ib = h1(t), ic = free
  int ia = 0, ib = 1, ic = 2;

  for (int t = 0; t < T; ++t) {
    const unsigned short* Ha = Hl + ia*HBUF;  // h0(t)
    const unsigned short* Hb = Hl + ib*HBUF;  // h1(t)
    unsigned short*       Hc = Hl + ic*HBUF;  // free -> h0(t+1)
    unsigned short*       HaW= Hl + ia*HBUF;  // retired after B1 -> h1(t+1)

    // ===== M1: gates0 = [x|1|h0] @ W0^T (bias in col 73), cell 0; h0n -> H[ic] =====
    #pragma unroll
    for (int p = 0; p < 2; ++p) {
      const unsigned short* wb = pk0i + ((size_t)((wv*2 + p)*NKT0)*64 + lane)*8;

      short8 wh[3][4];
      #pragma unroll
      for (int g = 0; g < 4; ++g) {
        const unsigned short* q0 = wb + (size_t)g*(16*NKT0*512);
        wh[0][g] = *(const short8*)(q0);
        wh[1][g] = *(const short8*)(q0 + 512);
      }

      f32x4 acc[4][4];
      #pragma unroll
      for (int mt = 0; mt < 4; ++mt)
        #pragma unroll
        for (int g = 0; g < 4; ++g) acc[mt][g] = (f32x4){0.f, 0.f, 0.f, 0.f};

      #pragma unroll
      for (int kt = 0; kt < NKT0; ++kt) {
        const int cb = kt % 3, nb2 = (kt + 2) % 3;
        if (kt + 2 < NKT0) {
          #pragma unroll
          for (int g = 0; g < 4; ++g)
            wh[nb2][g] = *(const short8*)(wb + (size_t)g*(16*NKT0*512) + (size_t)(kt+2)*512);
        }
        short8 a[4];
        if (kt < 3) {
          #pragma unroll
          for (int mt = 0; mt < 4; ++mt)
            a[mt] = *(const short8*)(Xl + (mt*16 + arow)*XSTR + kt*32 + koff);
        } else {
          #pragma unroll
          for (int mt = 0; mt < 4; ++mt)
            a[mt] = *(const short8*)(Ha + (mt*16 + arow)*HSTR + (kt - 3)*32 + koff);
        }
        #pragma unroll
        for (int g = 0; g < 4; ++g)
          #pragma unroll
          for (int mt = 0; mt < 4; ++mt)
            acc[mt][g] = __builtin_amdgcn_mfma_f32_16x16x32_bf16(a[mt], wh[cb][g], acc[mt][g], 0, 0, 0);
      }

      const int u = wv*32 + p*16 + (lane & 15);
      #pragma unroll
      for (int mt = 0; mt < 4; ++mt) {
        #pragma unroll
        for (int q = 0; q < 4; ++q) {
          float iv = sigm(acc[mt][0][q]);
          float fv = sigm(acc[mt][1][q]);
          float gv = ftanh(acc[mt][2][q]);
          float ov = sigm(acc[mt][3][q]);
          float cn = fv * c0s[(p*4 + mt)*4 + q] + iv * gv;
          c0s[(p*4 + mt)*4 + q] = cn;
          float hn = ov * ftanh(cn);
          int r = mt*16 + ((lane >> 4) << 2) + q;
          Hc[r*HSTR + u] = f2bf(hn);
        }
      }
    }
    __syncthreads();  // B1: h0n complete (H[ic]); H[ia] now dead

    // ===== M2: gates1 = [h0n|h1] @ W1^T (+b), cell 1; h1n -> H[ia] (retired) =====
    #pragma unroll
    for (int p = 0; p < 2; ++p) {
      const unsigned short* wb = pk1i + ((size_t)((wv*2 + p)*NKT1)*64 + lane)*8;

      short8 wh[3][4];
      #pragma unroll
      for (int g = 0; g < 4; ++g) {
        const unsigned short* q0 = wb + (size_t)g*(16*NKT1*512);
        wh[0][g] = *(const short8*)(q0);
        wh[1][g] = *(const short8*)(q0 + 512);
      }

      f32x4 acc[4][4];
      #pragma unroll
      for (int mt = 0; mt < 4; ++mt)
        #pragma unroll
        for (int g = 0; g < 4; ++g) {
          float b = bias1r[p*4 + g];
          acc[mt][g] = (f32x4){b, b, b, b};
        }

      #pragma unroll
      for (int kt = 0; kt < NKT1; ++kt) {
        const int cb = kt % 3, nb2 = (kt + 2) % 3;
        if (kt + 2 < NKT1) {
          #pragma unroll
          for (int g = 0; g < 4; ++g)
            wh[nb2][g] = *(const short8*)(wb + (size_t)g*(16*NKT1*512) + (size_t)(kt+2)*512);
        }
        short8 a[4];
        if (kt < 8) {
          #pragma unroll
          for (int mt = 0; mt < 4; ++mt)
            a[mt] = *(const short8*)(Hc + (mt*16 + arow)*HSTR + kt*32 + koff);
        } else {
          #pragma unroll
          for (int mt = 0; mt < 4; ++mt)
            a[mt] = *(const short8*)(Hb + (mt*16 + arow)*HSTR + (kt - 8)*32 + koff);
        }
        #pragma unroll
        for (int g = 0; g < 4; ++g)
          #pragma unroll
          for (int mt = 0; mt < 4; ++mt)
            acc[mt][g] = __builtin_amdgcn_mfma_f32_16x16x32_bf16(a[mt], wh[cb][g], acc[mt][g], 0, 0, 0);
      }

      const int u = wv*32 + p*16 + (lane & 15);
      #pragma unroll
      for (int mt = 0; mt < 4; ++mt) {
        #pragma unroll
        for (int q = 0; q < 4; ++q) {
          float iv = sigm(acc[mt][0][q]);
          float fv = sigm(acc[mt][1][q]);
          float gv = ftanh(acc[mt][2][q]);
          float ov = sigm(acc[mt][3][q]);
          float cn = fv * c1s[(p*4 + mt)*4 + q] + iv * gv;
          c1s[(p*4 + mt)*4 + q] = cn;
          float hn = ov * ftanh(cn);
          int r = mt*16 + ((lane >> 4) << 2) + q;
          HaW[r*HSTR + u] = f2bf(hn);   // write to retired h0(t) buffer: safe, no wave reads H[ia] now
        }
      }
    }
    __syncthreads();  // B2: h1n visible in H[ia]

    // ===== M3: hid = relu(h1n @ out_w1^T + out_b1) -> LDS fp32 =====
    {
      const unsigned short* wb = pkoi + ((size_t)(wv*NKTO)*64 + lane)*8;
      short8 wh[3];
      wh[0] = *(const short8*)(wb);
      wh[1] = *(const short8*)(wb + 512);

      f32x4 acc3[4];
      #pragma unroll
      for (int mt = 0; mt < 4; ++mt) acc3[mt] = (f32x4){ob1r, ob1r, ob1r, ob1r};

      #pragma unroll
      for (int kt = 0; kt < NKTO; ++kt) {
        const int cb = kt % 3, nb2 = (kt + 2) % 3;
        if (kt + 2 < NKTO)
          wh[nb2] = *(const short8*)(wb + (size_t)(kt+2)*512);
        short8 a[4];
        #pragma unroll
        for (int mt = 0; mt < 4; ++mt)
          a[mt] = *(const short8*)(HaW + (mt*16 + arow)*HSTR + kt*32 + koff);
        #pragma unroll
        for (int mt = 0; mt < 4; ++mt)
          acc3[mt] = __builtin_amdgcn_mfma_f32_16x16x32_bf16(a[mt], wh[cb], acc3[mt], 0, 0, 0);
      }
      const int uh = wv*16 + (lane & 15);
      #pragma unroll
      for (int mt = 0; mt < 4; ++mt)
        #pragma unroll
        for (int q = 0; q < 4; ++q) {
          float hv = fmaxf(acc3[mt][q], 0.f);
          int r = mt*16 + ((lane >> 4) << 2) + q;
          HIDl[r*HIDSTR + uh] = hv;
        }
    }
    __syncthreads();  // B4: hid visible

    // ===== M4: out = hid @ out_w2^T + out_b2, all 512 threads:
    // 8 threads per row, 16-wide k-partials, shfl-reduce width 8 =====
    {
      int r = tid >> 3, e = tid & 7;
      const float* hrow = HIDl + r*HIDSTR + e*16;
      float s0 = 0.f, s1 = 0.f, s2 = 0.f;
      #pragma unroll
      for (int k = 0; k < 16; ++k) {
        float hv = hrow[k];
        int kk = e*16 + k;
        s0 += hv * OW2l[kk];
        s1 += hv * OW2l[128 + kk];
        s2 += hv * OW2l[256 + kk];
      }
      #pragma unroll
      for (int d = 4; d; d >>= 1) {
        s0 += __shfl_down(s0, d, 8);
        s1 += __shfl_down(s1, d, 8);
        s2 += __shfl_down(s2, d, 8);
      }
      if (e == 0) {
        s0 += OB2l[0]; s1 += OB2l[1]; s2 += OB2l[2];
        int gr = row0 + r;
        float* orow = out + (size_t)gr * (T*3) + t*3;
        orow[0] = s0; orow[1] = s1; orow[2] = s2;
        Xl[r*XSTR + 0] = f2bf(s0);
        Xl[r*XSTR + 1] = f2bf(s1);
        Xl[r*XSTR + 2] = f2bf(s2);
      }
    }
    __syncthreads();  // B5: cur visible, hid reads done

    // rotate roles: h0(t+1) in old ic; h1(t+1) in old ia; old ib freed
    int tmp = ia; ia = ic; ic = ib; ib = tmp;
  }
}

extern "C" void kernel_launch(void* const* d_in, const int* in_sizes, int n_in,
                              void* d_out, int out_size, void* d_ws, size_t ws_size,
                              hipStream_t stream){
  const float* z    = (const float*)d_in[0];
  const float* cond = (const float*)d_in[1];
  const float* fiw  = (const float*)d_in[2];
  const float* fib  = (const float*)d_in[3];
  const float* wih0 = (const float*)d_in[4];
  const float* whh0 = (const float*)d_in[5];
  const float* bih0 = (const float*)d_in[6];
  const float* bhh0 = (const float*)d_in[7];
  const float* wih1 = (const float*)d_in[8];
  const float* whh1 = (const float*)d_in[9];
  const float* bih1 = (const float*)d_in[10];
  const float* bhh1 = (const float*)d_in[11];
  const float* ow1  = (const float*)d_in[12];
  const float* ob1  = (const float*)d_in[13];
  const float* ow2  = (const float*)d_in[14];
  const float* ob2  = (const float*)d_in[15];
  const int*   seqp = (const int*)d_in[16];
  unsigned short* wsb = (unsigned short*)d_ws;
  float* outp = (float*)d_out;

  hipFuncSetAttribute((const void*)traj_main,
                      hipFuncAttributeMaxDynamicSharedMemorySize, LDS_TOTAL);

  int packtot = PK0_ELEMS + PK1_ELEMS + PKO_ELEMS;
  pack_weights<<<(packtot + 255)/256, 256, 0, stream>>>(wih0, whh0, bih0, bhh0,
                                                        wih1, whh1, ow1, wsb);
  traj_main<<<16384/BROWS, NTHR, LDS_TOTAL, stream>>>(z, cond, fiw, fib,
                                                      bih1, bhh1,
                                                      ob1, ow2, ob2, wsb, seqp, outp);
}